// Round 16
// baseline (51.018 us; speedup 1.0000x reference)
//
#include <hip/hip_runtime.h>

#define NB 32
#define CC 3
#define HH 512
#define WW 512
#define KS 25
#define PAD 12
#define SEG 64                // output rows per block (8 groups of 8)
#define NG (SEG / 8)
#define LDSW2 268             // words per tile row: 6 halo + 256 + 6 halo (f16 pairs)

typedef __fp16 h2 __attribute__((ext_vector_type(2)));
typedef float vfloat4 __attribute__((ext_vector_type(4)));

#if __has_builtin(__builtin_amdgcn_fdot2)
#define FDOT2(a, b, c) __builtin_amdgcn_fdot2((a), (b), (c), false)
#else
#define FDOT2(a, b, c) ((float)(a).x * (float)(b).x + (float)(a).y * (float)(b).y + (c))
#endif

// normalized 1-D gaussian, sigma=9, K=25
__device__ constexpr float Wf[KS] = {
    0.02181520f, 0.02514307f, 0.02862302f, 0.03218484f, 0.03574584f,
    0.03921371f, 0.04249020f, 0.04547544f, 0.04807347f, 0.05019624f,
    0.05176967f, 0.05273727f, 0.05306384f, 0.05273727f, 0.05176967f,
    0.05019624f, 0.04807347f, 0.04547544f, 0.04249020f, 0.03921371f,
    0.03574584f, 0.03218484f, 0.02862302f, 0.02514307f, 0.02181520f};

__device__ constexpr float Wget(int t) {
    return (t >= 0 && t < KS) ? Wf[t] : 0.0f;
}

__device__ __forceinline__ float clamp01(float v) {
    return fminf(fmaxf(v, 0.0f), 1.0f);
}

// Rolling-register vertical blur (R15) + NT output stores (R16).
// NT theory: plain output writes allocate in L3 and evict the input
// (replay FETCH 66MB = input re-fetch). NT bypasses L3 -> input resident.
// (R4's NT "disaster" was actually (256,8)-forced spills; R5 proved it.)
template<bool EDGE>
__device__ __forceinline__ void body(const float* __restrict__ ibase,
                                     float* __restrict__ obase,
                                     int r0, int t, unsigned* tile16) {
    // zero tile halo words once: rows 0..7, words 0..5 and 262..267
    if (t < 8 * 12) {
        int r = t / 12;
        int k = t - r * 12;
        tile16[r * LDSW2 + (k < 6 ? k : 256 + k)] = 0u;
    }

    const float* ip = ibase + t * 2;
    h2 ringx[16], ringy[16];

    // ---- prologue: pairs s=0..15 = rows r0-12 .. r0+19 ----
#pragma unroll
    for (int s = 0; s < 16; ++s) {
        int rr0 = r0 - PAD + 2 * s;
        int rr1 = rr0 + 1;
        float2 va = make_float2(0.f, 0.f), vb = va;
        if (!EDGE || (rr0 >= 0 && rr0 < HH)) va = *(const float2*)(ip + (long)rr0 * WW);
        if (!EDGE || (rr1 >= 0 && rr1 < HH)) vb = *(const float2*)(ip + (long)rr1 * WW);
        ringx[s] = __builtin_amdgcn_cvt_pkrtz(va.x, vb.x);
        ringy[s] = __builtin_amdgcn_cvt_pkrtz(va.y, vb.y);
    }

#pragma unroll
    for (int g = 0; g < NG; ++g) {
        // issue next-group loads early (hidden under this group's compute)
        float2 nva[4], nvb[4];
        if (g < NG - 1) {
#pragma unroll
            for (int i = 0; i < 4; ++i) {
                int rr0 = r0 + 8 * g + 20 + 2 * i;   // rows 8g+20..8g+27
                int rr1 = rr0 + 1;
                nva[i] = make_float2(0.f, 0.f);
                nvb[i] = make_float2(0.f, 0.f);
                if (!EDGE || (rr0 >= 0 && rr0 < HH)) nva[i] = *(const float2*)(ip + (long)rr0 * WW);
                if (!EDGE || (rr1 >= 0 && rr1 < HH)) nvb[i] = *(const float2*)(ip + (long)rr1 * WW);
            }
        }

        // ---- vertical: 8 output rows from ring (taps t0 = 2m - j) ----
        float accx[8], accy[8];
#pragma unroll
        for (int j = 0; j < 8; ++j) { accx[j] = 0.f; accy[j] = 0.f; }
#pragma unroll
        for (int m = 0; m < 16; ++m) {
            const int slot = (4 * g + m) & 15;       // compile-time
            h2 px = ringx[slot], py = ringy[slot];
#pragma unroll
            for (int j = 0; j < 8; ++j) {
                const int t0 = 2 * m - j;            // compile-time
                if (t0 >= -1 && t0 <= 24) {
                    const h2 wp = {(__fp16)Wget(t0), (__fp16)Wget(t0 + 1)};
                    accx[j] = FDOT2(px, wp, accx[j]);
                    accy[j] = FDOT2(py, wp, accy[j]);
                }
            }
        }
#pragma unroll
        for (int j = 0; j < 8; ++j) {
            h2 w = __builtin_amdgcn_cvt_pkrtz(accx[j], accy[j]);
            tile16[j * LDSW2 + 6 + t] = __builtin_bit_cast(unsigned, w);
        }

        // commit next-group pairs into oldest slots (read above at m=0..3)
        if (g < NG - 1) {
#pragma unroll
            for (int i = 0; i < 4; ++i) {
                const int slot = (4 * g + i) & 15;   // compile-time
                ringx[slot] = __builtin_amdgcn_cvt_pkrtz(nva[i].x, nvb[i].x);
                ringy[slot] = __builtin_amdgcn_cvt_pkrtz(nva[i].y, nvb[i].y);
            }
        }

        __syncthreads();                             // tile16 ready

        // ---- horizontal + clip: 8 rows ----
#pragma unroll
        for (int it = 0; it < 2; ++it) {
            int f = it * 256 + t;
            int c = f & 63;                          // col group
            int row = f >> 6;                        // wave-uniform
            const unsigned* lp = &tile16[row * LDSW2 + 4 * c];
            h2 pa[16];
#pragma unroll
            for (int q = 0; q < 4; ++q) {            // 4x ds_read_b128
                uint4 u = *(const uint4*)(lp + 4 * q);
                pa[4 * q + 0] = __builtin_bit_cast(h2, u.x);
                pa[4 * q + 1] = __builtin_bit_cast(h2, u.y);
                pa[4 * q + 2] = __builtin_bit_cast(h2, u.z);
                pa[4 * q + 3] = __builtin_bit_cast(h2, u.w);
            }
            float res[8];
#pragma unroll
            for (int j = 0; j < 8; ++j) {
                float o = 0.f;
#pragma unroll
                for (int m = 0; m < 16; ++m) {
                    const int t0 = 2 * m - j;        // compile-time
                    if (t0 >= -1 && t0 <= 24) {
                        const h2 wp = {(__fp16)Wget(t0), (__fp16)Wget(t0 + 1)};
                        o = FDOT2(pa[m], wp, o);
                    }
                }
                res[j] = clamp01(o);
            }
            float* op = obase + (long)(r0 + 8 * g + row) * WW + 8 * c;
            vfloat4 o0 = {res[0], res[1], res[2], res[3]};
            vfloat4 o1 = {res[4], res[5], res[6], res[7]};
            __builtin_nontemporal_store(o0, (vfloat4*)(op + 0));
            __builtin_nontemporal_store(o1, (vfloat4*)(op + 4));
        }

        __syncthreads();                             // tile16 reusable
    }
}

__global__ __launch_bounds__(256, 4) void gblur_fused(const float* __restrict__ x,
                                                      float* __restrict__ out) {
    __shared__ unsigned tile16[8 * LDSW2];           // 8,576 B

    int t = threadIdx.x;

    // ---- block mapping with bijective XCD swizzle (768 % 8 == 0) ----
    int b = blockIdx.x;
    const int nwg = NB * CC * (HH / SEG);            // 768
    int per = nwg >> 3;
    int swz = (b & 7) * per + (b >> 3);
    int plane = swz >> 3;                            // 8 segments per plane
    int seg = swz & 7;
    int r0 = seg * SEG;

    const float* ibase = x + (long)plane * (HH * WW);
    float*       obase = out + (long)plane * (HH * WW);

    // only first/last segments touch the vertical image edges
    if (seg == 0 || seg == (HH / SEG) - 1)
        body<true>(ibase, obase, r0, t, tile16);
    else
        body<false>(ibase, obase, r0, t, tile16);
}

extern "C" void kernel_launch(void* const* d_in, const int* in_sizes, int n_in,
                              void* d_out, int out_size, void* d_ws, size_t ws_size,
                              hipStream_t stream) {
    const float* x = (const float*)d_in[0];
    float* out = (float*)d_out;
    const int nwg = NB * CC * (HH / SEG);            // 768 blocks
    gblur_fused<<<nwg, 256, 0, stream>>>(x, out);
}

// Round 17
// 44.732 us; speedup vs baseline: 1.1405x; 1.1405x over previous
//
#include <hip/hip_runtime.h>

#define NB 32
#define CC 3
#define HH 512
#define WW 512
#define KS 25
#define PAD 12
#define SEG 32                // output rows per block (4 groups of 8)
#define NG (SEG / 8)
#define LDSW2 268             // words per tile row: 6 halo + 256 + 6 halo (f16 pairs)
#define TILEW (8 * LDSW2)     // one buffer: 8 rows

typedef __fp16 h2 __attribute__((ext_vector_type(2)));

#if __has_builtin(__builtin_amdgcn_fdot2)
#define FDOT2(a, b, c) __builtin_amdgcn_fdot2((a), (b), (c), false)
#else
#define FDOT2(a, b, c) ((float)(a).x * (float)(b).x + (float)(a).y * (float)(b).y + (c))
#endif

// normalized 1-D gaussian, sigma=9, K=25
__device__ constexpr float Wf[KS] = {
    0.02181520f, 0.02514307f, 0.02862302f, 0.03218484f, 0.03574584f,
    0.03921371f, 0.04249020f, 0.04547544f, 0.04807347f, 0.05019624f,
    0.05176967f, 0.05273727f, 0.05306384f, 0.05273727f, 0.05176967f,
    0.05019624f, 0.04807347f, 0.04547544f, 0.04249020f, 0.03921371f,
    0.03574584f, 0.03218484f, 0.02862302f, 0.02514307f, 0.02181520f};

__device__ constexpr float Wget(int t) {
    return (t >= 0 && t < KS) ? Wf[t] : 0.0f;
}

__device__ __forceinline__ float clamp01(float v) {
    return fminf(fmaxf(v, 0.0f), 1.0f);
}

// R15 rolling-register vertical + R17 changes: SEG=32 (1536 blocks, 6/CU) and
// double-buffered LDS tile -> ONE barrier per group (write buf[g&1]; BAR;
// read buf[g&1]; next group writes the other buffer - WAR closed by the
// following barrier). NT stores are dead (R4/R16: write amplification).
template<bool EDGE>
__device__ __forceinline__ void body(const float* __restrict__ ibase,
                                     float* __restrict__ obase,
                                     int r0, int t, unsigned* tile16) {
    // zero halo words of BOTH buffers: 2 bufs x 8 rows x 12 words = 192 writes
    if (t < 2 * 8 * 12) {
        int buf = t / 96;
        int u = t - buf * 96;
        int r = u / 12;
        int k = u - r * 12;
        tile16[buf * TILEW + r * LDSW2 + (k < 6 ? k : 256 + k)] = 0u;
    }

    const float* ip = ibase + t * 2;
    h2 ringx[16], ringy[16];

    // ---- prologue: pairs s=0..15 = rows r0-12 .. r0+19 ----
#pragma unroll
    for (int s = 0; s < 16; ++s) {
        int rr0 = r0 - PAD + 2 * s;
        int rr1 = rr0 + 1;
        float2 va = make_float2(0.f, 0.f), vb = va;
        if (!EDGE || (rr0 >= 0 && rr0 < HH)) va = *(const float2*)(ip + (long)rr0 * WW);
        if (!EDGE || (rr1 >= 0 && rr1 < HH)) vb = *(const float2*)(ip + (long)rr1 * WW);
        ringx[s] = __builtin_amdgcn_cvt_pkrtz(va.x, vb.x);
        ringy[s] = __builtin_amdgcn_cvt_pkrtz(va.y, vb.y);
    }

#pragma unroll
    for (int g = 0; g < NG; ++g) {
        unsigned* buf = tile16 + (g & 1) * TILEW;

        // issue next-group loads early (hidden under this group's compute)
        float2 nva[4], nvb[4];
        if (g < NG - 1) {
#pragma unroll
            for (int i = 0; i < 4; ++i) {
                int rr0 = r0 + 8 * g + 20 + 2 * i;   // rows 8g+20..8g+27
                int rr1 = rr0 + 1;
                nva[i] = make_float2(0.f, 0.f);
                nvb[i] = make_float2(0.f, 0.f);
                if (!EDGE || (rr0 >= 0 && rr0 < HH)) nva[i] = *(const float2*)(ip + (long)rr0 * WW);
                if (!EDGE || (rr1 >= 0 && rr1 < HH)) nvb[i] = *(const float2*)(ip + (long)rr1 * WW);
            }
        }

        // ---- vertical: 8 output rows from ring (taps t0 = 2m - j) ----
        float accx[8], accy[8];
#pragma unroll
        for (int j = 0; j < 8; ++j) { accx[j] = 0.f; accy[j] = 0.f; }
#pragma unroll
        for (int m = 0; m < 16; ++m) {
            const int slot = (4 * g + m) & 15;       // compile-time
            h2 px = ringx[slot], py = ringy[slot];
#pragma unroll
            for (int j = 0; j < 8; ++j) {
                const int t0 = 2 * m - j;            // compile-time
                if (t0 >= -1 && t0 <= 24) {
                    const h2 wp = {(__fp16)Wget(t0), (__fp16)Wget(t0 + 1)};
                    accx[j] = FDOT2(px, wp, accx[j]);
                    accy[j] = FDOT2(py, wp, accy[j]);
                }
            }
        }
#pragma unroll
        for (int j = 0; j < 8; ++j) {
            h2 w = __builtin_amdgcn_cvt_pkrtz(accx[j], accy[j]);
            buf[j * LDSW2 + 6 + t] = __builtin_bit_cast(unsigned, w);
        }

        // commit next-group pairs into oldest slots (read above at m=0..3)
        if (g < NG - 1) {
#pragma unroll
            for (int i = 0; i < 4; ++i) {
                const int slot = (4 * g + i) & 15;   // compile-time
                ringx[slot] = __builtin_amdgcn_cvt_pkrtz(nva[i].x, nvb[i].x);
                ringy[slot] = __builtin_amdgcn_cvt_pkrtz(nva[i].y, nvb[i].y);
            }
        }

        __syncthreads();                             // buf ready (only barrier)

        // ---- horizontal + clip: 8 rows ----
#pragma unroll
        for (int it = 0; it < 2; ++it) {
            int f = it * 256 + t;
            int c = f & 63;                          // col group
            int row = f >> 6;                        // wave-uniform
            const unsigned* lp = &buf[row * LDSW2 + 4 * c];
            h2 pa[16];
#pragma unroll
            for (int q = 0; q < 4; ++q) {            // 4x ds_read_b128
                uint4 u = *(const uint4*)(lp + 4 * q);
                pa[4 * q + 0] = __builtin_bit_cast(h2, u.x);
                pa[4 * q + 1] = __builtin_bit_cast(h2, u.y);
                pa[4 * q + 2] = __builtin_bit_cast(h2, u.z);
                pa[4 * q + 3] = __builtin_bit_cast(h2, u.w);
            }
            float res[8];
#pragma unroll
            for (int j = 0; j < 8; ++j) {
                float o = 0.f;
#pragma unroll
                for (int m = 0; m < 16; ++m) {
                    const int t0 = 2 * m - j;        // compile-time
                    if (t0 >= -1 && t0 <= 24) {
                        const h2 wp = {(__fp16)Wget(t0), (__fp16)Wget(t0 + 1)};
                        o = FDOT2(pa[m], wp, o);
                    }
                }
                res[j] = clamp01(o);
            }
            float* op = obase + (long)(r0 + 8 * g + row) * WW + 8 * c;
            *(float4*)(op + 0) = make_float4(res[0], res[1], res[2], res[3]);
            *(float4*)(op + 4) = make_float4(res[4], res[5], res[6], res[7]);
        }
        // no second barrier: next group writes the other buffer; the next
        // group's barrier closes the WAR on this one.
    }
}

__global__ __launch_bounds__(256, 4) void gblur_fused(const float* __restrict__ x,
                                                      float* __restrict__ out) {
    __shared__ unsigned tile16[2 * TILEW];           // 17,152 B

    int t = threadIdx.x;

    // ---- block mapping with bijective XCD swizzle (1536 % 8 == 0) ----
    int b = blockIdx.x;
    const int nwg = NB * CC * (HH / SEG);            // 1536
    int per = nwg >> 3;
    int swz = (b & 7) * per + (b >> 3);
    int plane = swz >> 4;                            // 16 segments per plane
    int seg = swz & 15;
    int r0 = seg * SEG;

    const float* ibase = x + (long)plane * (HH * WW);
    float*       obase = out + (long)plane * (HH * WW);

    // only first/last segments touch the vertical image edges
    if (seg == 0 || seg == (HH / SEG) - 1)
        body<true>(ibase, obase, r0, t, tile16);
    else
        body<false>(ibase, obase, r0, t, tile16);
}

extern "C" void kernel_launch(void* const* d_in, const int* in_sizes, int n_in,
                              void* d_out, int out_size, void* d_ws, size_t ws_size,
                              hipStream_t stream) {
    const float* x = (const float*)d_in[0];
    float* out = (float*)d_out;
    const int nwg = NB * CC * (HH / SEG);            // 1536 blocks
    gblur_fused<<<nwg, 256, 0, stream>>>(x, out);
}

// Round 18
// 40.497 us; speedup vs baseline: 1.2598x; 1.1046x over previous
//
#include <hip/hip_runtime.h>

#define NB 32
#define CC 3
#define HH 512
#define WW 512
#define KS 25
#define PAD 12
#define SEG 64                // output rows per block (8 groups of 8)
#define NG (SEG / 8)
#define LDSW2 268             // words per tile row: 6 halo + 256 + 6 halo (f16 pairs)

typedef __fp16 h2 __attribute__((ext_vector_type(2)));

#if __has_builtin(__builtin_amdgcn_fdot2)
#define FDOT2(a, b, c) __builtin_amdgcn_fdot2((a), (b), (c), false)
#else
#define FDOT2(a, b, c) ((float)(a).x * (float)(b).x + (float)(a).y * (float)(b).y + (c))
#endif

// normalized 1-D gaussian, sigma=9, K=25
__device__ constexpr float Wf[KS] = {
    0.02181520f, 0.02514307f, 0.02862302f, 0.03218484f, 0.03574584f,
    0.03921371f, 0.04249020f, 0.04547544f, 0.04807347f, 0.05019624f,
    0.05176967f, 0.05273727f, 0.05306384f, 0.05273727f, 0.05176967f,
    0.05019624f, 0.04807347f, 0.04547544f, 0.04249020f, 0.03921371f,
    0.03574584f, 0.03218484f, 0.02862302f, 0.02514307f, 0.02181520f};

__device__ constexpr float Wget(int t) {
    return (t >= 0 && t < KS) ? Wf[t] : 0.0f;
}

__device__ __forceinline__ float clamp01(float v) {
    return fminf(fmaxf(v, 0.0f), 1.0f);
}

// FINAL (R15 = best of 17 rounds, 40.5us): rolling-register vertical blur --
// each input row loaded from global ONCE per block (amp 1.375x), f16-pair
// dot2 arithmetic, LDS f16 tile for the horizontal pass, plain f4 stores.
// Ceiling evidence: eff. HBM BW 3.5-4.05 TB/s across structures with
// occupancy 24-63% (anti-correlated -> saturated memory system);
// floor = 98MB writes + ~50MB L3-thrash refetch at ~4 TB/s ~= 36.5us.
// Dead ends (measured): NT stores (write-amplify 98->118/590MB, R4/R16);
// launch_bounds(256,8) (spills, R5); 1024-thr blocks (occ drop, R13);
// SEG=32 halo amp (R17); forced MLP via sched_barrier (null, R9).
template<bool EDGE>
__device__ __forceinline__ void body(const float* __restrict__ ibase,
                                     float* __restrict__ obase,
                                     int r0, int t, unsigned* tile16) {
    // zero tile halo words once: rows 0..7, words 0..5 and 262..267
    if (t < 8 * 12) {
        int r = t / 12;
        int k = t - r * 12;
        tile16[r * LDSW2 + (k < 6 ? k : 256 + k)] = 0u;
    }

    const float* ip = ibase + t * 2;
    h2 ringx[16], ringy[16];

    // ---- prologue: pairs s=0..15 = rows r0-12 .. r0+19 ----
#pragma unroll
    for (int s = 0; s < 16; ++s) {
        int rr0 = r0 - PAD + 2 * s;
        int rr1 = rr0 + 1;
        float2 va = make_float2(0.f, 0.f), vb = va;
        if (!EDGE || (rr0 >= 0 && rr0 < HH)) va = *(const float2*)(ip + (long)rr0 * WW);
        if (!EDGE || (rr1 >= 0 && rr1 < HH)) vb = *(const float2*)(ip + (long)rr1 * WW);
        ringx[s] = __builtin_amdgcn_cvt_pkrtz(va.x, vb.x);
        ringy[s] = __builtin_amdgcn_cvt_pkrtz(va.y, vb.y);
    }

#pragma unroll
    for (int g = 0; g < NG; ++g) {
        // issue next-group loads early (hidden under this group's compute)
        float2 nva[4], nvb[4];
        if (g < NG - 1) {
#pragma unroll
            for (int i = 0; i < 4; ++i) {
                int rr0 = r0 + 8 * g + 20 + 2 * i;   // rows 8g+20..8g+27
                int rr1 = rr0 + 1;
                nva[i] = make_float2(0.f, 0.f);
                nvb[i] = make_float2(0.f, 0.f);
                if (!EDGE || (rr0 >= 0 && rr0 < HH)) nva[i] = *(const float2*)(ip + (long)rr0 * WW);
                if (!EDGE || (rr1 >= 0 && rr1 < HH)) nvb[i] = *(const float2*)(ip + (long)rr1 * WW);
            }
        }

        // ---- vertical: 8 output rows from ring (taps t0 = 2m - j) ----
        float accx[8], accy[8];
#pragma unroll
        for (int j = 0; j < 8; ++j) { accx[j] = 0.f; accy[j] = 0.f; }
#pragma unroll
        for (int m = 0; m < 16; ++m) {
            const int slot = (4 * g + m) & 15;       // compile-time
            h2 px = ringx[slot], py = ringy[slot];
#pragma unroll
            for (int j = 0; j < 8; ++j) {
                const int t0 = 2 * m - j;            // compile-time
                if (t0 >= -1 && t0 <= 24) {
                    const h2 wp = {(__fp16)Wget(t0), (__fp16)Wget(t0 + 1)};
                    accx[j] = FDOT2(px, wp, accx[j]);
                    accy[j] = FDOT2(py, wp, accy[j]);
                }
            }
        }
#pragma unroll
        for (int j = 0; j < 8; ++j) {
            h2 w = __builtin_amdgcn_cvt_pkrtz(accx[j], accy[j]);
            tile16[j * LDSW2 + 6 + t] = __builtin_bit_cast(unsigned, w);
        }

        // commit next-group pairs into oldest slots (read above at m=0..3)
        if (g < NG - 1) {
#pragma unroll
            for (int i = 0; i < 4; ++i) {
                const int slot = (4 * g + i) & 15;   // compile-time
                ringx[slot] = __builtin_amdgcn_cvt_pkrtz(nva[i].x, nvb[i].x);
                ringy[slot] = __builtin_amdgcn_cvt_pkrtz(nva[i].y, nvb[i].y);
            }
        }

        __syncthreads();                             // tile16 ready

        // ---- horizontal + clip: 8 rows ----
#pragma unroll
        for (int it = 0; it < 2; ++it) {
            int f = it * 256 + t;
            int c = f & 63;                          // col group
            int row = f >> 6;                        // wave-uniform
            const unsigned* lp = &tile16[row * LDSW2 + 4 * c];
            h2 pa[16];
#pragma unroll
            for (int q = 0; q < 4; ++q) {            // 4x ds_read_b128
                uint4 u = *(const uint4*)(lp + 4 * q);
                pa[4 * q + 0] = __builtin_bit_cast(h2, u.x);
                pa[4 * q + 1] = __builtin_bit_cast(h2, u.y);
                pa[4 * q + 2] = __builtin_bit_cast(h2, u.z);
                pa[4 * q + 3] = __builtin_bit_cast(h2, u.w);
            }
            float res[8];
#pragma unroll
            for (int j = 0; j < 8; ++j) {
                float o = 0.f;
#pragma unroll
                for (int m = 0; m < 16; ++m) {
                    const int t0 = 2 * m - j;        // compile-time
                    if (t0 >= -1 && t0 <= 24) {
                        const h2 wp = {(__fp16)Wget(t0), (__fp16)Wget(t0 + 1)};
                        o = FDOT2(pa[m], wp, o);
                    }
                }
                res[j] = clamp01(o);
            }
            float* op = obase + (long)(r0 + 8 * g + row) * WW + 8 * c;
            *(float4*)(op + 0) = make_float4(res[0], res[1], res[2], res[3]);
            *(float4*)(op + 4) = make_float4(res[4], res[5], res[6], res[7]);
        }

        __syncthreads();                             // tile16 reusable
    }
}

__global__ __launch_bounds__(256, 4) void gblur_fused(const float* __restrict__ x,
                                                      float* __restrict__ out) {
    __shared__ unsigned tile16[8 * LDSW2];           // 8,576 B

    int t = threadIdx.x;

    // ---- block mapping with bijective XCD swizzle (768 % 8 == 0) ----
    int b = blockIdx.x;
    const int nwg = NB * CC * (HH / SEG);            // 768
    int per = nwg >> 3;
    int swz = (b & 7) * per + (b >> 3);
    int plane = swz >> 3;                            // 8 segments per plane
    int seg = swz & 7;
    int r0 = seg * SEG;

    const float* ibase = x + (long)plane * (HH * WW);
    float*       obase = out + (long)plane * (HH * WW);

    // only first/last segments touch the vertical image edges
    if (seg == 0 || seg == (HH / SEG) - 1)
        body<true>(ibase, obase, r0, t, tile16);
    else
        body<false>(ibase, obase, r0, t, tile16);
}

extern "C" void kernel_launch(void* const* d_in, const int* in_sizes, int n_in,
                              void* d_out, int out_size, void* d_ws, size_t ws_size,
                              hipStream_t stream) {
    const float* x = (const float*)d_in[0];
    float* out = (float*)d_out;
    const int nwg = NB * CC * (HH / SEG);            // 768 blocks
    gblur_fused<<<nwg, 256, 0, stream>>>(x, out);
}